// Round 3
// baseline (405.423 us; speedup 1.0000x reference)
//
#include <hip/hip_runtime.h>
#include <stdint.h>
#include <math.h>

typedef unsigned short u16;
typedef __attribute__((ext_vector_type(8))) __bf16 v8bf;
typedef v8bf __attribute__((may_alias)) v8bf_a;
typedef __attribute__((ext_vector_type(4))) float v4f;
typedef __attribute__((ext_vector_type(4))) u16 v4u16;
typedef v4u16 __attribute__((may_alias)) v4u16_a;
typedef __attribute__((ext_vector_type(8))) u16 v8u16;
typedef v8u16 __attribute__((may_alias)) v8u16_a;

__device__ __forceinline__ float bf2f(u16 u) {
    union { uint32_t i; float f; } c; c.i = ((uint32_t)u) << 16; return c.f;
}
__device__ __forceinline__ u16 f2bf(float f) {
    union { float f; uint32_t i; } c; c.f = f;
    return (u16)((c.i + 0x7FFFu + ((c.i >> 16) & 1u)) >> 16);
}
__device__ __forceinline__ void gl_lds16(const u16* g, u16* l) {
    __builtin_amdgcn_global_load_lds(
        (const __attribute__((address_space(1))) void*)g,
        (__attribute__((address_space(3))) void*)l, 16, 0, 0);
}

// ---------------------------------------------------------------------------
// fp32 -> bf16 conversion (inputs are fp32: proven by round-2/3 NaN bisect).
// ---------------------------------------------------------------------------
__global__ __launch_bounds__(256) void convert_bf16(
    const float* __restrict__ src, u16* __restrict__ dst, int n)
{
    const int stride = gridDim.x * blockDim.x;
    for (int i = blockIdx.x * blockDim.x + threadIdx.x; i * 8 < n; i += stride) {
        const int base = i * 8;
        v8u16 o;
#pragma unroll
        for (int j = 0; j < 8; j++) o[j] = f2bf(src[base + j]);
        *(v8u16_a*)(dst + base) = o;
    }
}

// ---------------------------------------------------------------------------
// B^T GEMM, pipelined: C[m][n] = sum_k A[m][k] * W[n][k].
// BM=BN=256, BK=32, 512 threads = 8 waves (2M x 4N), wave-tile 128x64.
// 3 LDS buffers (96 KiB), prefetch distance 2, counted s_waitcnt vmcnt(4),
// raw s_barrier.  LDS layout fragment-major -> linear zero-conflict reads.
// ---------------------------------------------------------------------------
template <bool F32OUT>
__global__ __launch_bounds__(512) void gemm_p3(
    const u16* __restrict__ A, int lda,
    const u16* __restrict__ W0, const u16* __restrict__ W1, const u16* __restrict__ W2,
    int n1, int n2, void* __restrict__ Cv, int ldc, int K)
{
    __shared__ __align__(16) u16 lds[3][16384];   // per buf: A 8192 u16, B 8192 u16
    const int t  = threadIdx.x;
    const int m0 = blockIdx.x * 256, n0 = blockIdx.y * 256;

    const u16* W; int nw;
    if (n0 < n1)      { W = W0; nw = n0; }
    else if (n0 < n2) { W = W1; nw = n0 - n1; }
    else              { W = W2; nw = n0 - n2; }

    // staging sources for chunks c0 = t, c1 = 512 + t
    const int c0 = t, c1 = 512 + t;
    const int ra0 = ((c0 >> 6) << 4) + (c0 & 15), ca0 = ((c0 >> 4) & 3) << 3;
    const int ra1 = ((c1 >> 6) << 4) + (c1 & 15), ca1 = ((c1 >> 4) & 3) << 3;
    const u16* sa0 = A + (size_t)(m0 + ra0) * lda + ca0;
    const u16* sa1 = A + (size_t)(m0 + ra1) * lda + ca1;
    const u16* sb0 = W + (size_t)(nw + ra0) * K   + ca0;
    const u16* sb1 = W + (size_t)(nw + ra1) * K   + ca1;

#define STAGE_P3(koff, dst)                                  \
    do {                                                     \
        gl_lds16(sa0 + (koff), (dst) + c0 * 8);              \
        gl_lds16(sa1 + (koff), (dst) + c1 * 8);              \
        gl_lds16(sb0 + (koff), (dst) + 8192 + c0 * 8);       \
        gl_lds16(sb1 + (koff), (dst) + 8192 + c1 * 8);       \
    } while (0)

    const int NT = K >> 5;             // 32-wide K tiles
    STAGE_P3(0,  lds[0]);              // prologue: tiles 0,1 in flight (8 loads)
    STAGE_P3(32, lds[1]);

    const int wid = t >> 6, lane = t & 63;
    const int l15 = lane & 15, quad = lane >> 4;
    const int wr8 = (wid >> 2) << 3;   // A frag-block base (x8)
    const int wc4 = (wid & 3) << 2;    // B frag-block base (x4)
    const int lofs = lane << 3;        // lane*8 u16 = lane*16 B

    v4f acc[8][4] = {};
    int bb = 0;
    for (int kt = 0; kt < NT; ++kt) {
        // tile kt's 4 loads are the oldest; tile kt+1's 4 stay in flight
        if (kt < NT - 1) asm volatile("s_waitcnt vmcnt(4)" ::: "memory");
        else             asm volatile("s_waitcnt vmcnt(0)" ::: "memory");
        __builtin_amdgcn_s_barrier();   // all waves' tile-kt data visible;
                                        // all waves done reading buf (bb+2)%3
        if (kt + 2 < NT) {
            int nb = bb + 2; if (nb >= 3) nb -= 3;
            STAGE_P3((kt + 2) * 32, lds[nb]);
        }
        const u16* Ab = lds[bb];
        const u16* Bb = Ab + 8192;
        v8bf af[8], bv[4];
#pragma unroll
        for (int i = 0; i < 8; i++) af[i] = *(const v8bf_a*)(Ab + ((wr8 + i) << 9) + lofs);
#pragma unroll
        for (int j = 0; j < 4; j++) bv[j] = *(const v8bf_a*)(Bb + ((wc4 + j) << 9) + lofs);
        __builtin_amdgcn_s_setprio(1);
#pragma unroll
        for (int i = 0; i < 8; i++)
#pragma unroll
            for (int j = 0; j < 4; j++)
                acc[i][j] = __builtin_amdgcn_mfma_f32_16x16x32_bf16(af[i], bv[j], acc[i][j], 0, 0, 0);
        __builtin_amdgcn_s_setprio(0);
        bb = (bb == 2) ? 0 : bb + 1;
    }
#undef STAGE_P3

#pragma unroll
    for (int i = 0; i < 8; i++)
#pragma unroll
        for (int j = 0; j < 4; j++)
#pragma unroll
            for (int r = 0; r < 4; r++) {
                const int row = m0 + (wr8 + i) * 16 + quad * 4 + r;
                const int col = n0 + (wc4 + j) * 16 + l15;
                if (F32OUT) ((float*)Cv)[(size_t)row * ldc + col] = acc[i][j][r];
                else        ((u16*)Cv)[(size_t)row * ldc + col]   = f2bf(acc[i][j][r]);
            }
}

// ---------------------------------------------------------------------------
// RMSNorm + RoPE on q (16 heads) and k (8 heads), IN-PLACE on qkv.
// ---------------------------------------------------------------------------
__global__ __launch_bounds__(256) void normrope(
    u16* __restrict__ qkv, const u16* __restrict__ qw, const u16* __restrict__ kw)
{
    const int tok = blockIdx.x;
    const int s = tok & 2047;
    const int wid = threadIdx.x >> 6, lane = threadIdx.x & 63;
    const int d  = lane * 2;
    const int dm = d & 63;
    const float kln = 9.210340371976184f / 64.f;
    const float inv0 = expf(-(float)dm * kln);
    const float inv1 = expf(-(float)(dm + 1) * kln);
    float sn0, cs0, sn1, cs1;
    __sincosf((float)s * inv0, &sn0, &cs0);
    __sincosf((float)s * inv1, &sn1, &cs1);

    for (int task = wid; task < 24; task += 4) {
        const bool isq = task < 16;
        const int  hh  = isq ? task : task - 16;
        u16* p = qkv + (size_t)tok * 4096 + (isq ? hh * 128 : 2048 + hh * 128) + d;
        const float x0 = bf2f(p[0]), x1 = bf2f(p[1]);
        float ss = x0 * x0 + x1 * x1;
#pragma unroll
        for (int off = 32; off; off >>= 1) ss += __shfl_xor(ss, off);
        const float rr = rsqrtf(ss * (1.f / 128.f) + 1e-6f);
        const u16* wp = (isq ? qw : kw) + d;
        const float xn0 = x0 * rr * (1.f + bf2f(wp[0]));
        const float xn1 = x1 * rr * (1.f + bf2f(wp[1]));
        const float pp0 = __shfl_xor(xn0, 32);
        const float pp1 = __shfl_xor(xn1, 32);
        float o0, o1;
        if (lane < 32) { o0 = xn0 * cs0 - pp0 * sn0; o1 = xn1 * cs1 - pp1 * sn1; }
        else           { o0 = xn0 * cs0 + pp0 * sn0; o1 = xn1 * cs1 + pp1 * sn1; }
        p[0] = f2bf(o0); p[1] = f2bf(o1);
    }
}

// ---------------------------------------------------------------------------
// V transpose: qkv v-cols [tok][3072 + c]  ->  v_t[b*1024 + c][s]
// ---------------------------------------------------------------------------
__global__ __launch_bounds__(256) void vtrans(
    const u16* __restrict__ qkv, u16* __restrict__ v_t)
{
    __shared__ __align__(16) u16 tile[64][80];
    const int b = blockIdx.x, st = blockIdx.y * 64, ct = blockIdx.z * 64;
    const int t = threadIdx.x;
    {
        const int sl = t >> 2, cq = (t & 3) * 16;
        const u16* src = qkv + ((size_t)(b * 2048 + st + sl)) * 4096 + 3072 + ct + cq;
        *(v8u16_a*)&tile[sl][cq]     = *(const v8u16_a*)src;
        *(v8u16_a*)&tile[sl][cq + 8] = *(const v8u16_a*)(src + 8);
    }
    __syncthreads();
    {
        const int dl = t >> 2, sq = (t & 3) * 16;
        v8u16 o0, o1;
#pragma unroll
        for (int i = 0; i < 8; i++) { o0[i] = tile[sq + i][dl]; o1[i] = tile[sq + 8 + i][dl]; }
        u16* dst = v_t + ((size_t)(b * 1024 + ct + dl)) * 2048 + st + sq;
        *(v8u16_a*)dst       = o0;
        *(v8u16_a*)(dst + 8) = o1;
    }
}

// ---------------------------------------------------------------------------
// Flash attention, sliding window 1024, GQA groups=2. Block = 64 queries x 1
// head (4 waves x 16 q). K tiles (32x128) staged via global_load_lds
// (XOR-swizzled), double-buffered, one __syncthreads per tile.
// Round-2 changes (softmax de-bookkeeping):
//  * FIXED exponent bias instead of online max: RMSNorm bounds |s|<=128
//    (Cauchy-Schwarz, |q|2=|k|2=sqrt(128)), so s*kSc*log2e in [-16.4,16.4].
//    p = exp2(s*kSc2 - 20) is overflow/underflow-free and softmax is exactly
//    bias-invariant. Deletes max-tree, per-tile shfl reduces, defer-max,
//    alpha rescale -- and the serial cross-lane chain between QK and exp.
//  * l_i is a per-lane partial, reduced ONCE at the epilogue (2 shfls total).
//  * interior tiles (kt+31<=qw0 && kt>=qw0-1008) skip the ~40-inst mask block
//    (wave-uniform branch); boundary tiles keep the -inf path (exp2(-inf)=0).
//  * s_setprio(1) around QK and PV MFMA clusters (T5, +4-7% attn per m191).
// ---------------------------------------------------------------------------
__global__ __launch_bounds__(256) void attn_fa(
    const u16* __restrict__ qkv,   // [tok][4096]
    const u16* __restrict__ v_t,   // [b*1024 + kvh*128+d][2048]
    u16* __restrict__ attn)        // [tok][h*128+d]
{
    __shared__ __align__(16) u16 Ks[2][32 * 128];
    __shared__ __align__(16) u16 p_lds[4][16 * 72];
    const int bh = blockIdx.x;
    const int b = bh >> 4, h = bh & 15, kvh = h >> 1;
    const int t = threadIdx.x;
    const int wid = t >> 6, lane = t & 63;
    const int l15 = lane & 15, quad = lane >> 4;
    const int qb0 = ((int)gridDim.y - 1 - (int)blockIdx.y) * 64;  // heavy first
    const int qw0 = qb0 + wid * 16;
    const int q   = qw0 + l15;

    const u16* Qb = qkv + ((size_t)(b * 2048 + q)) * 4096 + h * 128 + quad * 8;
    v8bf qf[4];
#pragma unroll
    for (int kc = 0; kc < 4; kc++) qf[kc] = *(const v8bf_a*)(Qb + kc * 32);

    const u16* Kb = qkv + (size_t)b * 2048 * 4096 + 2048 + kvh * 128;
    const u16* Vb = v_t + (size_t)(b * 1024 + kvh * 128) * 2048;

    // block-uniform K range
    int ks = qb0 - 1023; if (ks < 0) ks = 0;
    const int kstart = ks & ~31, kend = qb0 + 63;

    // staging map: thread t covers (row, chunk16) = (t>>4, t&15) and (+16, same)
    const int sr0 = t >> 4, sc = t & 15, sr1 = sr0 + 16;
    const int so0 = (sc ^ (sr0 & 7)) * 8;   // swizzled source col (u16)
    const int so1 = (sc ^ (sr1 & 7)) * 8;

    gl_lds16(Kb + (size_t)(kstart + sr0) * 4096 + so0, &Ks[0][(size_t)t * 8]);
    gl_lds16(Kb + (size_t)(kstart + sr1) * 4096 + so1, &Ks[0][(size_t)(256 + t) * 8]);

    v4f o[8] = {};             // O^T: d = nt*16 + quad*4 + r, query = l15
    float l_i = 0.f;           // per-lane partial sum (this lane's 8 key slots)
    const float kSc2 = 0.12754245006257017f;  // (1/sqrt(128)) * log2(e)
    const float BIAS = 20.0f;                 // fixed exp2 bias, > 16.4 bound
    u16* P = &p_lds[wid][0];
    const int swz = l15 & 7;

    int buf = 0;
    for (int kt = kstart; kt <= kend; kt += 32, buf ^= 1) {
        __syncthreads();   // staging of `buf` complete; prior reads of buf^1 done
        if (kt + 32 <= kend) {
            gl_lds16(Kb + (size_t)(kt + 32 + sr0) * 4096 + so0, &Ks[buf ^ 1][(size_t)t * 8]);
            gl_lds16(Kb + (size_t)(kt + 32 + sr1) * 4096 + so1, &Ks[buf ^ 1][(size_t)(256 + t) * 8]);
        }
        // wave-uniform: skip tiles fully masked for this wave's 16 queries
        if (kt > qw0 + 15 || kt + 31 <= qw0 - 1024) continue;

        // V fragments: issue early, overlap with QK + softmax
        v8bf vf[8];
        const u16* Vr = Vb + (size_t)l15 * 2048 + kt + quad * 8;
#pragma unroll
        for (int nt = 0; nt < 8; nt++) vf[nt] = *(const v8bf_a*)(Vr + (size_t)nt * 16 * 2048);

        // QK from swizzled LDS: rows l15 / l15+16, d-chunk (kc*4+quad)^swz
        v4f s0 = {}, s1 = {};
        const u16* K0 = &Ks[buf][(size_t)l15 * 128];
        const u16* K1 = K0 + 16 * 128;
        __builtin_amdgcn_s_setprio(1);
#pragma unroll
        for (int kc = 0; kc < 4; kc++) {
            const int cs = ((kc * 4 + quad) ^ swz) * 8;
            s0 = __builtin_amdgcn_mfma_f32_16x16x32_bf16(*(const v8bf_a*)(K0 + cs), qf[kc], s0, 0, 0, 0);
            s1 = __builtin_amdgcn_mfma_f32_16x16x32_bf16(*(const v8bf_a*)(K1 + cs), qf[kc], s1, 0, 0, 0);
        }
        __builtin_amdgcn_s_setprio(0);

        // p = exp2(s*kSc2 - BIAS); masked -> -inf -> 0.  No max tracking.
        float p[8];
        if (kt + 31 <= qw0 && kt >= qw0 - 1008) {
            // interior tile: fully inside window for all 16 queries of wave
#pragma unroll
            for (int r = 0; r < 4; r++) { p[r] = s0[r]; p[r + 4] = s1[r]; }
        } else {
#pragma unroll
            for (int r = 0; r < 4; r++) {
                const int kk0 = kt + quad * 4 + r, kk1 = kk0 + 16;
                p[r]     = (kk0 <= q && kk0 > q - 1024) ? s0[r] : -INFINITY;
                p[r + 4] = (kk1 <= q && kk1 > q - 1024) ? s1[r] : -INFINITY;
            }
        }
        float ps = 0.f;
#pragma unroll
        for (int j = 0; j < 8; j++) {
            p[j] = __builtin_amdgcn_exp2f(__builtin_fmaf(p[j], kSc2, -BIAS));
            ps += p[j];
        }
        l_i += ps;

        // P^T -> per-wave LDS via HW packed cvt: row = query l15 (stride 72)
        union { v4u16 v; uint32_t d[2]; } u0, u1;
        asm("v_cvt_pk_bf16_f32 %0, %1, %2" : "=v"(u0.d[0]) : "v"(p[0]), "v"(p[1]));
        asm("v_cvt_pk_bf16_f32 %0, %1, %2" : "=v"(u0.d[1]) : "v"(p[2]), "v"(p[3]));
        asm("v_cvt_pk_bf16_f32 %0, %1, %2" : "=v"(u1.d[0]) : "v"(p[4]), "v"(p[5]));
        asm("v_cvt_pk_bf16_f32 %0, %1, %2" : "=v"(u1.d[1]) : "v"(p[6]), "v"(p[7]));
        *(v4u16_a*)(P + l15 * 72 + quad * 4)      = u0.v;
        *(v4u16_a*)(P + l15 * 72 + 16 + quad * 4) = u1.v;

        asm volatile("s_waitcnt lgkmcnt(0)" ::: "memory");
        const v8bf pf = *(const v8bf_a*)(P + l15 * 72 + quad * 8);  // B-frag of P^T
        __builtin_amdgcn_s_setprio(1);
#pragma unroll
        for (int nt = 0; nt < 8; nt++)
            o[nt] = __builtin_amdgcn_mfma_f32_16x16x32_bf16(vf[nt], pf, o[nt], 0, 0, 0);
        __builtin_amdgcn_s_setprio(0);
    }

    // epilogue: reduce l across the 4 quad-lanes of each query, then scale
    l_i += __shfl_xor(l_i, 16);
    l_i += __shfl_xor(l_i, 32);
    const float inv = 1.0f / l_i;
    u16* orow = attn + ((size_t)(b * 2048 + q)) * 2048 + h * 128 + quad * 4;
#pragma unroll
    for (int nt = 0; nt < 8; nt++) {
        v4u16 ov;
#pragma unroll
        for (int r = 0; r < 4; r++) ov[r] = f2bf(o[nt][r] * inv);
        *(v4u16_a*)(orow + nt * 16) = ov;
    }
}

// ---------------------------------------------------------------------------
extern "C" void kernel_launch(void* const* d_in, const int* in_sizes, int n_in,
                              void* d_out, int out_size, void* d_ws, size_t ws_size,
                              hipStream_t stream)
{
    // workspace layout (u16 elements)
    u16* qkv  = (u16*)d_ws;                            // [4096][4096]
    u16* v_t  = qkv  + (size_t)16777216;               // [2048][2048]
    u16* xa   = v_t  + (size_t)4194304;                // x_bf16, later attn
    u16* wbf  = xa   + (size_t)8388608;                // wq|wk|wv, later wo
    u16* nwq  = wbf  + (size_t)8388608;                // 128
    u16* nwk  = nwq  + 128;                            // 128

    // 0) materialize bf16 copies of fp32 inputs
    convert_bf16<<<4096, 256, 0, stream>>>((const float*)d_in[0], xa,            8388608); // x
    convert_bf16<<<2048, 256, 0, stream>>>((const float*)d_in[1], wbf,           4194304); // wq
    convert_bf16<<<1024, 256, 0, stream>>>((const float*)d_in[2], wbf + 4194304, 2097152); // wk
    convert_bf16<<<1024, 256, 0, stream>>>((const float*)d_in[3], wbf + 6291456, 2097152); // wv
    convert_bf16<<<1,    256, 0, stream>>>((const float*)d_in[5], nwq,           128);     // q_norm
    convert_bf16<<<1,    256, 0, stream>>>((const float*)d_in[6], nwk,           128);     // k_norm
    // 1) fused QKV projection (pipelined 256x256 tiles)
    gemm_p3<false><<<dim3(16, 16), 512, 0, stream>>>(xa, 2048, wbf, wbf + 4194304, wbf + 6291456,
                                                     2048, 3072, qkv, 4096, 2048);
    // 2) wo -> bf16, overwriting the now-dead wq slot
    convert_bf16<<<2048, 256, 0, stream>>>((const float*)d_in[4], wbf, 4194304);
    // 3) RMSNorm + RoPE for q,k (in-place)
    normrope<<<dim3(4096), 256, 0, stream>>>(qkv, nwq, nwk);
    // 4) V transpose for PV A-operand
    vtrans<<<dim3(2, 32, 16), 256, 0, stream>>>(qkv, v_t);
    // 5) sliding-window flash attention (attn overwrites dead x_bf16)
    attn_fa<<<dim3(32, 32), 256, 0, stream>>>(qkv, v_t, xa);
    // 6) output projection -> d_out as FP32 (reference output dtype)
    gemm_p3<true><<<dim3(16, 8), 512, 0, stream>>>(xa, 2048, wbf, wbf, wbf,
                                                   4096, 4096, d_out, 2048, 2048);
}

// Round 4
// 404.192 us; speedup vs baseline: 1.0030x; 1.0030x over previous
//
#include <hip/hip_runtime.h>
#include <stdint.h>
#include <math.h>

typedef unsigned short u16;
typedef __attribute__((ext_vector_type(8))) __bf16 v8bf;
typedef v8bf __attribute__((may_alias)) v8bf_a;
typedef __attribute__((ext_vector_type(4))) float v4f;
typedef __attribute__((ext_vector_type(4))) u16 v4u16;
typedef v4u16 __attribute__((may_alias)) v4u16_a;
typedef __attribute__((ext_vector_type(8))) u16 v8u16;
typedef v8u16 __attribute__((may_alias)) v8u16_a;

__device__ __forceinline__ float bf2f(u16 u) {
    union { uint32_t i; float f; } c; c.i = ((uint32_t)u) << 16; return c.f;
}
__device__ __forceinline__ u16 f2bf(float f) {
    union { float f; uint32_t i; } c; c.f = f;
    return (u16)((c.i + 0x7FFFu + ((c.i >> 16) & 1u)) >> 16);
}
__device__ __forceinline__ void gl_lds16(const u16* g, u16* l) {
    __builtin_amdgcn_global_load_lds(
        (const __attribute__((address_space(1))) void*)g,
        (__attribute__((address_space(3))) void*)l, 16, 0, 0);
}

// ---------------------------------------------------------------------------
// fp32 -> bf16 conversion (inputs are fp32: proven by round-2/3 NaN bisect).
// ---------------------------------------------------------------------------
__global__ __launch_bounds__(256) void convert_bf16(
    const float* __restrict__ src, u16* __restrict__ dst, int n)
{
    const int stride = gridDim.x * blockDim.x;
    for (int i = blockIdx.x * blockDim.x + threadIdx.x; i * 8 < n; i += stride) {
        const int base = i * 8;
        v8u16 o;
#pragma unroll
        for (int j = 0; j < 8; j++) o[j] = f2bf(src[base + j]);
        *(v8u16_a*)(dst + base) = o;
    }
}

// ---------------------------------------------------------------------------
// B^T GEMM, pipelined: C[m][n] = sum_k A[m][k] * W[n][k].
// BM=BN=256, BK=32, 512 threads = 8 waves (2M x 4N), wave-tile 128x64.
// 3 LDS buffers (96 KiB), prefetch distance 2, counted s_waitcnt vmcnt(4),
// raw s_barrier.  LDS layout fragment-major -> linear zero-conflict reads.
// ---------------------------------------------------------------------------
template <bool F32OUT>
__global__ __launch_bounds__(512) void gemm_p3(
    const u16* __restrict__ A, int lda,
    const u16* __restrict__ W0, const u16* __restrict__ W1, const u16* __restrict__ W2,
    int n1, int n2, void* __restrict__ Cv, int ldc, int K)
{
    __shared__ __align__(16) u16 lds[3][16384];   // per buf: A 8192 u16, B 8192 u16
    const int t  = threadIdx.x;
    const int m0 = blockIdx.x * 256, n0 = blockIdx.y * 256;

    const u16* W; int nw;
    if (n0 < n1)      { W = W0; nw = n0; }
    else if (n0 < n2) { W = W1; nw = n0 - n1; }
    else              { W = W2; nw = n0 - n2; }

    // staging sources for chunks c0 = t, c1 = 512 + t
    const int c0 = t, c1 = 512 + t;
    const int ra0 = ((c0 >> 6) << 4) + (c0 & 15), ca0 = ((c0 >> 4) & 3) << 3;
    const int ra1 = ((c1 >> 6) << 4) + (c1 & 15), ca1 = ((c1 >> 4) & 3) << 3;
    const u16* sa0 = A + (size_t)(m0 + ra0) * lda + ca0;
    const u16* sa1 = A + (size_t)(m0 + ra1) * lda + ca1;
    const u16* sb0 = W + (size_t)(nw + ra0) * K   + ca0;
    const u16* sb1 = W + (size_t)(nw + ra1) * K   + ca1;

#define STAGE_P3(koff, dst)                                  \
    do {                                                     \
        gl_lds16(sa0 + (koff), (dst) + c0 * 8);              \
        gl_lds16(sa1 + (koff), (dst) + c1 * 8);              \
        gl_lds16(sb0 + (koff), (dst) + 8192 + c0 * 8);       \
        gl_lds16(sb1 + (koff), (dst) + 8192 + c1 * 8);       \
    } while (0)

    const int NT = K >> 5;             // 32-wide K tiles
    STAGE_P3(0,  lds[0]);              // prologue: tiles 0,1 in flight (8 loads)
    STAGE_P3(32, lds[1]);

    const int wid = t >> 6, lane = t & 63;
    const int l15 = lane & 15, quad = lane >> 4;
    const int wr8 = (wid >> 2) << 3;   // A frag-block base (x8)
    const int wc4 = (wid & 3) << 2;    // B frag-block base (x4)
    const int lofs = lane << 3;        // lane*8 u16 = lane*16 B

    v4f acc[8][4] = {};
    int bb = 0;
    for (int kt = 0; kt < NT; ++kt) {
        // tile kt's 4 loads are the oldest; tile kt+1's 4 stay in flight
        if (kt < NT - 1) asm volatile("s_waitcnt vmcnt(4)" ::: "memory");
        else             asm volatile("s_waitcnt vmcnt(0)" ::: "memory");
        __builtin_amdgcn_s_barrier();   // all waves' tile-kt data visible;
                                        // all waves done reading buf (bb+2)%3
        if (kt + 2 < NT) {
            int nb = bb + 2; if (nb >= 3) nb -= 3;
            STAGE_P3((kt + 2) * 32, lds[nb]);
        }
        const u16* Ab = lds[bb];
        const u16* Bb = Ab + 8192;
        v8bf af[8], bv[4];
#pragma unroll
        for (int i = 0; i < 8; i++) af[i] = *(const v8bf_a*)(Ab + ((wr8 + i) << 9) + lofs);
#pragma unroll
        for (int j = 0; j < 4; j++) bv[j] = *(const v8bf_a*)(Bb + ((wc4 + j) << 9) + lofs);
        __builtin_amdgcn_s_setprio(1);
#pragma unroll
        for (int i = 0; i < 8; i++)
#pragma unroll
            for (int j = 0; j < 4; j++)
                acc[i][j] = __builtin_amdgcn_mfma_f32_16x16x32_bf16(af[i], bv[j], acc[i][j], 0, 0, 0);
        __builtin_amdgcn_s_setprio(0);
        bb = (bb == 2) ? 0 : bb + 1;
    }
#undef STAGE_P3

#pragma unroll
    for (int i = 0; i < 8; i++)
#pragma unroll
        for (int j = 0; j < 4; j++)
#pragma unroll
            for (int r = 0; r < 4; r++) {
                const int row = m0 + (wr8 + i) * 16 + quad * 4 + r;
                const int col = n0 + (wc4 + j) * 16 + l15;
                if (F32OUT) ((float*)Cv)[(size_t)row * ldc + col] = acc[i][j][r];
                else        ((u16*)Cv)[(size_t)row * ldc + col]   = f2bf(acc[i][j][r]);
            }
}

// ---------------------------------------------------------------------------
// RMSNorm + RoPE on q (16 heads) and k (8 heads), IN-PLACE on qkv.
// ---------------------------------------------------------------------------
__global__ __launch_bounds__(256) void normrope(
    u16* __restrict__ qkv, const u16* __restrict__ qw, const u16* __restrict__ kw)
{
    const int tok = blockIdx.x;
    const int s = tok & 2047;
    const int wid = threadIdx.x >> 6, lane = threadIdx.x & 63;
    const int d  = lane * 2;
    const int dm = d & 63;
    const float kln = 9.210340371976184f / 64.f;
    const float inv0 = expf(-(float)dm * kln);
    const float inv1 = expf(-(float)(dm + 1) * kln);
    float sn0, cs0, sn1, cs1;
    __sincosf((float)s * inv0, &sn0, &cs0);
    __sincosf((float)s * inv1, &sn1, &cs1);

    for (int task = wid; task < 24; task += 4) {
        const bool isq = task < 16;
        const int  hh  = isq ? task : task - 16;
        u16* p = qkv + (size_t)tok * 4096 + (isq ? hh * 128 : 2048 + hh * 128) + d;
        const float x0 = bf2f(p[0]), x1 = bf2f(p[1]);
        float ss = x0 * x0 + x1 * x1;
#pragma unroll
        for (int off = 32; off; off >>= 1) ss += __shfl_xor(ss, off);
        const float rr = rsqrtf(ss * (1.f / 128.f) + 1e-6f);
        const u16* wp = (isq ? qw : kw) + d;
        const float xn0 = x0 * rr * (1.f + bf2f(wp[0]));
        const float xn1 = x1 * rr * (1.f + bf2f(wp[1]));
        const float pp0 = __shfl_xor(xn0, 32);
        const float pp1 = __shfl_xor(xn1, 32);
        float o0, o1;
        if (lane < 32) { o0 = xn0 * cs0 - pp0 * sn0; o1 = xn1 * cs1 - pp1 * sn1; }
        else           { o0 = xn0 * cs0 + pp0 * sn0; o1 = xn1 * cs1 + pp1 * sn1; }
        p[0] = f2bf(o0); p[1] = f2bf(o1);
    }
}

// ---------------------------------------------------------------------------
// V transpose: qkv v-cols [tok][3072 + c]  ->  v_t[b*1024 + c][s]
// ---------------------------------------------------------------------------
__global__ __launch_bounds__(256) void vtrans(
    const u16* __restrict__ qkv, u16* __restrict__ v_t)
{
    __shared__ __align__(16) u16 tile[64][80];
    const int b = blockIdx.x, st = blockIdx.y * 64, ct = blockIdx.z * 64;
    const int t = threadIdx.x;
    {
        const int sl = t >> 2, cq = (t & 3) * 16;
        const u16* src = qkv + ((size_t)(b * 2048 + st + sl)) * 4096 + 3072 + ct + cq;
        *(v8u16_a*)&tile[sl][cq]     = *(const v8u16_a*)src;
        *(v8u16_a*)&tile[sl][cq + 8] = *(const v8u16_a*)(src + 8);
    }
    __syncthreads();
    {
        const int dl = t >> 2, sq = (t & 3) * 16;
        v8u16 o0, o1;
#pragma unroll
        for (int i = 0; i < 8; i++) { o0[i] = tile[sq + i][dl]; o1[i] = tile[sq + 8 + i][dl]; }
        u16* dst = v_t + ((size_t)(b * 1024 + ct + dl)) * 2048 + st + sq;
        *(v8u16_a*)dst       = o0;
        *(v8u16_a*)(dst + 8) = o1;
    }
}

// ---------------------------------------------------------------------------
// Flash attention, sliding window 1024, GQA groups=2. Block = 64 queries x 1
// head (4 waves x 16 q).
// Round-3 change: KVBLK 32 -> 64 (latency-bound diagnosis: all pipes idle,
// makespan = heavy-block serial rounds x per-round fixed latency).  Halves
// rounds (34 -> ~17), halves barriers/prefetch/lgkm-waits per unit work; the
// two 32-key halves inside a round give ILP so the P LDS round-trip of half0
// overlaps exp/QK of half1.  setprio REMOVED from attn (4-wave lockstep =
// m190's negative case; round-2 regression suspect).  Fixed-bias softmax
// kept (RMSNorm bounds |s|*kSc*log2e <= 16.4; bias 20; softmax invariant).
// LDS: Ks 2 x [64][128] (32 KB) + P 4 x 2 x [16][72] (18 KB) -> 3 blocks/CU.
// ---------------------------------------------------------------------------
__global__ __launch_bounds__(256) void attn_fa(
    const u16* __restrict__ qkv,   // [tok][4096]
    const u16* __restrict__ v_t,   // [b*1024 + kvh*128+d][2048]
    u16* __restrict__ attn)        // [tok][h*128+d]
{
    __shared__ __align__(16) u16 Ks[2][64 * 128];
    __shared__ __align__(16) u16 p_lds[4][2 * 16 * 72];
    const int bh = blockIdx.x;
    const int b = bh >> 4, h = bh & 15, kvh = h >> 1;
    const int t = threadIdx.x;
    const int wid = t >> 6, lane = t & 63;
    const int l15 = lane & 15, quad = lane >> 4;
    const int qb0 = ((int)gridDim.y - 1 - (int)blockIdx.y) * 64;  // heavy first
    const int qw0 = qb0 + wid * 16;
    const int q   = qw0 + l15;

    const u16* Qb = qkv + ((size_t)(b * 2048 + q)) * 4096 + h * 128 + quad * 8;
    v8bf qf[4];
#pragma unroll
    for (int kc = 0; kc < 4; kc++) qf[kc] = *(const v8bf_a*)(Qb + kc * 32);

    const u16* Kb = qkv + (size_t)b * 2048 * 4096 + 2048 + kvh * 128;
    const u16* Vb = v_t + (size_t)(b * 1024 + kvh * 128) * 2048;

    // block-uniform K range, 64-aligned
    int ks = qb0 - 1023; if (ks < 0) ks = 0;
    const int kstart = ks & ~63, kend = qb0 + 63;

    // staging: 64 rows x 16 chunks(16B) = 1024 slots, 4 per thread.
    // thread t covers rows sr, sr+16, sr+32, sr+48 at chunk sc; swizzle key
    // (row & 7) is identical for all four (16 = 0 mod 8).
    const int sr = t >> 4, sc = t & 15;
    const int so = (sc ^ (sr & 7)) * 8;          // swizzled source col (u16)
    const u16* Ksrc = Kb + (size_t)sr * 4096 + so;

#define STAGEK(buf_, ktv)                                                     \
    do {                                                                      \
        const u16* gp_ = Ksrc + (size_t)(ktv) * 4096;                         \
        gl_lds16(gp_,                      &Ks[buf_][(size_t)t * 8]);         \
        gl_lds16(gp_ + (size_t)16 * 4096,  &Ks[buf_][(size_t)(t + 256) * 8]); \
        gl_lds16(gp_ + (size_t)32 * 4096,  &Ks[buf_][(size_t)(t + 512) * 8]); \
        gl_lds16(gp_ + (size_t)48 * 4096,  &Ks[buf_][(size_t)(t + 768) * 8]); \
    } while (0)

    STAGEK(0, kstart);

    v4f o[8] = {};             // O^T: d = nt*16 + quad*4 + r, query = l15
    float l_i = 0.f;           // per-lane partial sum (this lane's key slots)
    const float kSc2 = 0.12754245006257017f;  // (1/sqrt(128)) * log2(e)
    const float BIAS = 20.0f;                 // fixed exp2 bias, > 16.4 bound
    u16* P = &p_lds[wid][0];   // two [16][72] half-tiles (half1 at +1152)
    const int swz = l15 & 7;

    int buf = 0;
    for (int kt = kstart; kt <= kend; kt += 64, buf ^= 1) {
        __syncthreads();   // staging of `buf` complete; prior reads of buf^1 done
        if (kt + 64 <= kend) STAGEK(buf ^ 1, kt + 64);

        // wave-uniform: skip rounds fully masked for this wave's 16 queries
        if (kt > qw0 + 15 || kt + 63 <= qw0 - 1024) continue;

        // V fragments for both halves: issue early, overlap with QK + softmax
        v8bf vf0[8], vf1[8];
        const u16* Vr = Vb + (size_t)l15 * 2048 + kt + quad * 8;
#pragma unroll
        for (int nt = 0; nt < 8; nt++) {
            vf0[nt] = *(const v8bf_a*)(Vr + (size_t)nt * 16 * 2048);
            vf1[nt] = *(const v8bf_a*)(Vr + 32 + (size_t)nt * 16 * 2048);
        }

        // QK for 4 key sub-rows (l15 + 16j), swizzled chunk (kc*4+quad)^swz
        v4f s[4] = {{}, {}, {}, {}};
        const u16* Kr = &Ks[buf][(size_t)l15 * 128];
#pragma unroll
        for (int kc = 0; kc < 4; kc++) {
            const int cs = ((kc * 4 + quad) ^ swz) * 8;
            s[0] = __builtin_amdgcn_mfma_f32_16x16x32_bf16(*(const v8bf_a*)(Kr + cs), qf[kc], s[0], 0, 0, 0);
            s[1] = __builtin_amdgcn_mfma_f32_16x16x32_bf16(*(const v8bf_a*)(Kr + 16 * 128 + cs), qf[kc], s[1], 0, 0, 0);
            s[2] = __builtin_amdgcn_mfma_f32_16x16x32_bf16(*(const v8bf_a*)(Kr + 32 * 128 + cs), qf[kc], s[2], 0, 0, 0);
            s[3] = __builtin_amdgcn_mfma_f32_16x16x32_bf16(*(const v8bf_a*)(Kr + 48 * 128 + cs), qf[kc], s[3], 0, 0, 0);
        }

        // p = exp2(s*kSc2 - BIAS); masked -> -inf -> 0.  No max tracking.
        float p[16];
        if (kt + 63 <= qw0 && kt >= qw0 - 1008) {
            // interior round: fully inside window for all 16 queries of wave
#pragma unroll
            for (int j = 0; j < 4; j++)
#pragma unroll
                for (int r = 0; r < 4; r++) p[j * 4 + r] = s[j][r];
        } else {
#pragma unroll
            for (int j = 0; j < 4; j++)
#pragma unroll
                for (int r = 0; r < 4; r++) {
                    const int kk = kt + j * 16 + quad * 4 + r;
                    p[j * 4 + r] = (kk <= q && kk > q - 1024) ? s[j][r] : -INFINITY;
                }
        }
        float ps = 0.f;
#pragma unroll
        for (int j = 0; j < 16; j++) {
            p[j] = __builtin_amdgcn_exp2f(__builtin_fmaf(p[j], kSc2, -BIAS));
            ps += p[j];
        }
        l_i += ps;

        // P^T -> per-wave LDS via HW packed cvt: row = query l15 (stride 72)
        union { v4u16 v; uint32_t d[2]; } u0, u1, u2, u3;
        asm("v_cvt_pk_bf16_f32 %0, %1, %2" : "=v"(u0.d[0]) : "v"(p[0]),  "v"(p[1]));
        asm("v_cvt_pk_bf16_f32 %0, %1, %2" : "=v"(u0.d[1]) : "v"(p[2]),  "v"(p[3]));
        asm("v_cvt_pk_bf16_f32 %0, %1, %2" : "=v"(u1.d[0]) : "v"(p[4]),  "v"(p[5]));
        asm("v_cvt_pk_bf16_f32 %0, %1, %2" : "=v"(u1.d[1]) : "v"(p[6]),  "v"(p[7]));
        asm("v_cvt_pk_bf16_f32 %0, %1, %2" : "=v"(u2.d[0]) : "v"(p[8]),  "v"(p[9]));
        asm("v_cvt_pk_bf16_f32 %0, %1, %2" : "=v"(u2.d[1]) : "v"(p[10]), "v"(p[11]));
        asm("v_cvt_pk_bf16_f32 %0, %1, %2" : "=v"(u3.d[0]) : "v"(p[12]), "v"(p[13]));
        asm("v_cvt_pk_bf16_f32 %0, %1, %2" : "=v"(u3.d[1]) : "v"(p[14]), "v"(p[15]));
        *(v4u16_a*)(P + l15 * 72 + quad * 4)               = u0.v;  // half0, keys 0..15
        *(v4u16_a*)(P + l15 * 72 + 16 + quad * 4)          = u1.v;  // half0, keys 16..31
        *(v4u16_a*)(P + 1152 + l15 * 72 + quad * 4)        = u2.v;  // half1, keys 32..47
        *(v4u16_a*)(P + 1152 + l15 * 72 + 16 + quad * 4)   = u3.v;  // half1, keys 48..63

        asm volatile("s_waitcnt lgkmcnt(0)" ::: "memory");
        const v8bf pf0 = *(const v8bf_a*)(P + l15 * 72 + quad * 8);
        const v8bf pf1 = *(const v8bf_a*)(P + 1152 + l15 * 72 + quad * 8);
#pragma unroll
        for (int nt = 0; nt < 8; nt++)
            o[nt] = __builtin_amdgcn_mfma_f32_16x16x32_bf16(vf0[nt], pf0, o[nt], 0, 0, 0);
#pragma unroll
        for (int nt = 0; nt < 8; nt++)
            o[nt] = __builtin_amdgcn_mfma_f32_16x16x32_bf16(vf1[nt], pf1, o[nt], 0, 0, 0);
    }
#undef STAGEK

    // epilogue: reduce l across the 4 quad-lanes of each query, then scale
    l_i += __shfl_xor(l_i, 16);
    l_i += __shfl_xor(l_i, 32);
    const float inv = 1.0f / l_i;
    u16* orow = attn + ((size_t)(b * 2048 + q)) * 2048 + h * 128 + quad * 4;
#pragma unroll
    for (int nt = 0; nt < 8; nt++) {
        v4u16 ov;
#pragma unroll
        for (int r = 0; r < 4; r++) ov[r] = f2bf(o[nt][r] * inv);
        *(v4u16_a*)(orow + nt * 16) = ov;
    }
}

// ---------------------------------------------------------------------------
extern "C" void kernel_launch(void* const* d_in, const int* in_sizes, int n_in,
                              void* d_out, int out_size, void* d_ws, size_t ws_size,
                              hipStream_t stream)
{
    // workspace layout (u16 elements)
    u16* qkv  = (u16*)d_ws;                            // [4096][4096]
    u16* v_t  = qkv  + (size_t)16777216;               // [2048][2048]
    u16* xa   = v_t  + (size_t)4194304;                // x_bf16, later attn
    u16* wbf  = xa   + (size_t)8388608;                // wq|wk|wv, later wo
    u16* nwq  = wbf  + (size_t)8388608;                // 128
    u16* nwk  = nwq  + 128;                            // 128

    // 0) materialize bf16 copies of fp32 inputs
    convert_bf16<<<4096, 256, 0, stream>>>((const float*)d_in[0], xa,            8388608); // x
    convert_bf16<<<2048, 256, 0, stream>>>((const float*)d_in[1], wbf,           4194304); // wq
    convert_bf16<<<1024, 256, 0, stream>>>((const float*)d_in[2], wbf + 4194304, 2097152); // wk
    convert_bf16<<<1024, 256, 0, stream>>>((const float*)d_in[3], wbf + 6291456, 2097152); // wv
    convert_bf16<<<1,    256, 0, stream>>>((const float*)d_in[5], nwq,           128);     // q_norm
    convert_bf16<<<1,    256, 0, stream>>>((const float*)d_in[6], nwk,           128);     // k_norm
    // 1) fused QKV projection (pipelined 256x256 tiles)
    gemm_p3<false><<<dim3(16, 16), 512, 0, stream>>>(xa, 2048, wbf, wbf + 4194304, wbf + 6291456,
                                                     2048, 3072, qkv, 4096, 2048);
    // 2) wo -> bf16, overwriting the now-dead wq slot
    convert_bf16<<<2048, 256, 0, stream>>>((const float*)d_in[4], wbf, 4194304);
    // 3) RMSNorm + RoPE for q,k (in-place)
    normrope<<<dim3(4096), 256, 0, stream>>>(qkv, nwq, nwk);
    // 4) V transpose for PV A-operand
    vtrans<<<dim3(2, 32, 16), 256, 0, stream>>>(qkv, v_t);
    // 5) sliding-window flash attention (attn overwrites dead x_bf16)
    attn_fa<<<dim3(32, 32), 256, 0, stream>>>(qkv, v_t, xa);
    // 6) output projection -> d_out as FP32 (reference output dtype)
    gemm_p3<true><<<dim3(16, 8), 512, 0, stream>>>(xa, 2048, wbf, wbf, wbf,
                                                   4096, 4096, d_out, 2048, 2048);
}